// Round 2
// baseline (3664.507 us; speedup 1.0000x reference)
//
#include <hip/hip_runtime.h>
#include <math.h>

// Problem constants
constexpr int B_ = 8, T_ = 1024, S_ = 256, C_ = 1024, H_ = 16, F_ = 4096, D_ = 64;

// ---------------------------------------------------------------------------
// LayerNorm: one block per row (C=1024), 256 threads, float4 per thread.
// jnp.var is biased (/N); eps inside rsqrt — matches reference.
// ---------------------------------------------------------------------------
__global__ __launch_bounds__(256) void ln_kernel(
    const float* __restrict__ x, const float* __restrict__ g,
    const float* __restrict__ b, float* __restrict__ out) {
  const int row = blockIdx.x;
  const int t = threadIdx.x;
  const float4 v = reinterpret_cast<const float4*>(x + (size_t)row * C_)[t];
  float sum = v.x + v.y + v.z + v.w;
  float ss  = v.x * v.x + v.y * v.y + v.z * v.z + v.w * v.w;
#pragma unroll
  for (int o = 1; o < 64; o <<= 1) {
    sum += __shfl_xor(sum, o);
    ss  += __shfl_xor(ss, o);
  }
  __shared__ float s1[4], s2[4];
  const int wid = t >> 6;
  if ((t & 63) == 0) { s1[wid] = sum; s2[wid] = ss; }
  __syncthreads();
  sum = s1[0] + s1[1] + s1[2] + s1[3];
  ss  = s2[0] + s2[1] + s2[2] + s2[3];
  const float inv = 1.0f / (float)C_;
  const float mu  = sum * inv;
  const float var = ss * inv - mu * mu;
  const float rstd = rsqrtf(var + 1e-5f);
  const float4 gg = reinterpret_cast<const float4*>(g)[t];
  const float4 bb = reinterpret_cast<const float4*>(b)[t];
  float4 o4;
  o4.x = (v.x - mu) * rstd * gg.x + bb.x;
  o4.y = (v.y - mu) * rstd * gg.y + bb.y;
  o4.z = (v.z - mu) * rstd * gg.z + bb.z;
  o4.w = (v.w - mu) * rstd * gg.w + bb.w;
  reinterpret_cast<float4*>(out + (size_t)row * C_)[t] = o4;
}

// ---------------------------------------------------------------------------
// fp32 tiled GEMM: C[M,N] = A[M,K] @ W[K,N] (+bias) (+resid | gelu)
// 128x128 tile, BK=16, 256 threads, 8x8 per thread as 2x2 quadrants of 4x4.
// LDS rows padded to 132 floats (float4-aligned). Inner reads <=2-way.
// Requires: M%128==0, N%128==0, K%16==0 (true for all call sites).
// ---------------------------------------------------------------------------
enum { EPI_NONE = 0, EPI_BIAS_RESID = 1, EPI_BIAS_GELU = 2 };

__device__ __forceinline__ float gelu_exact(float v) {
  return 0.5f * v * (1.0f + erff(v * 0.70710678118654752440f));
}

__device__ __forceinline__ void fma4x4(float (&c)[4][4], const float4 a, const float4 b) {
  c[0][0] += a.x * b.x; c[0][1] += a.x * b.y; c[0][2] += a.x * b.z; c[0][3] += a.x * b.w;
  c[1][0] += a.y * b.x; c[1][1] += a.y * b.y; c[1][2] += a.y * b.z; c[1][3] += a.y * b.w;
  c[2][0] += a.z * b.x; c[2][1] += a.z * b.y; c[2][2] += a.z * b.z; c[2][3] += a.z * b.w;
  c[3][0] += a.w * b.x; c[3][1] += a.w * b.y; c[3][2] += a.w * b.z; c[3][3] += a.w * b.w;
}

template <int EPI>
__global__ __launch_bounds__(256) void gemm_kernel(
    const float* __restrict__ A, const float* __restrict__ W,
    const float* __restrict__ bias, const float* __restrict__ resid,
    float* __restrict__ Co, int M, int N, int K) {
  __shared__ float As[16][132];  // As[k][m] (A staged transposed)
  __shared__ float Bs[16][132];  // Bs[k][n]
  const int bn = blockIdx.x * 128;
  const int bm = blockIdx.y * 128;
  const int tid = threadIdx.x;
  const int tx = tid & 15, ty = tid >> 4;

  float acc[2][2][4][4] = {{{{0.f}}}};

  const int ar = tid >> 1;           // A tile row 0..127
  const int ak = (tid & 1) * 8;      // k offset 0 or 8
  const int bk = tid >> 4;           // B tile k-row 0..15
  const int bno = (tid & 15) * 8;    // B col offset 0..120

  const float* Ap = A + (size_t)(bm + ar) * K + ak;
  const float* Wp = W + (size_t)bk * N + bn + bno;

  for (int k0 = 0; k0 < K; k0 += 16) {
    const float4 a0 = *reinterpret_cast<const float4*>(Ap + k0);
    const float4 a1 = *reinterpret_cast<const float4*>(Ap + k0 + 4);
    const float4 b0 = *reinterpret_cast<const float4*>(Wp + (size_t)k0 * N);
    const float4 b1 = *reinterpret_cast<const float4*>(Wp + (size_t)k0 * N + 4);
    __syncthreads();  // previous iteration's LDS reads complete
    As[ak + 0][ar] = a0.x; As[ak + 1][ar] = a0.y;
    As[ak + 2][ar] = a0.z; As[ak + 3][ar] = a0.w;
    As[ak + 4][ar] = a1.x; As[ak + 5][ar] = a1.y;
    As[ak + 6][ar] = a1.z; As[ak + 7][ar] = a1.w;
    *reinterpret_cast<float4*>(&Bs[bk][bno])     = b0;
    *reinterpret_cast<float4*>(&Bs[bk][bno + 4]) = b1;
    __syncthreads();
#pragma unroll
    for (int k = 0; k < 16; ++k) {
      const float4 aLo = *reinterpret_cast<const float4*>(&As[k][ty * 4]);
      const float4 aHi = *reinterpret_cast<const float4*>(&As[k][64 + ty * 4]);
      const float4 bLo = *reinterpret_cast<const float4*>(&Bs[k][tx * 4]);
      const float4 bHi = *reinterpret_cast<const float4*>(&Bs[k][64 + tx * 4]);
      fma4x4(acc[0][0], aLo, bLo); fma4x4(acc[0][1], aLo, bHi);
      fma4x4(acc[1][0], aHi, bLo); fma4x4(acc[1][1], aHi, bHi);
    }
  }

  const int n0 = bn + tx * 4;
  float4 bias4[2];
  bias4[0] = make_float4(0.f, 0.f, 0.f, 0.f);
  bias4[1] = bias4[0];
  if (EPI != EPI_NONE) {
    bias4[0] = *reinterpret_cast<const float4*>(bias + n0);
    bias4[1] = *reinterpret_cast<const float4*>(bias + n0 + 64);
  }
#pragma unroll
  for (int p = 0; p < 2; ++p) {
#pragma unroll
    for (int i = 0; i < 4; ++i) {
      const size_t m = (size_t)(bm + p * 64 + ty * 4 + i);
#pragma unroll
      for (int q = 0; q < 2; ++q) {
        const int nc = n0 + q * 64;
        float4 o;
        o.x = acc[p][q][i][0] + bias4[q].x;
        o.y = acc[p][q][i][1] + bias4[q].y;
        o.z = acc[p][q][i][2] + bias4[q].z;
        o.w = acc[p][q][i][3] + bias4[q].w;
        if (EPI == EPI_BIAS_GELU) {
          o.x = gelu_exact(o.x); o.y = gelu_exact(o.y);
          o.z = gelu_exact(o.z); o.w = gelu_exact(o.w);
        }
        if (EPI == EPI_BIAS_RESID) {
          const float4 r = *reinterpret_cast<const float4*>(resid + m * N + nc);
          o.x += r.x; o.y += r.y; o.z += r.z; o.w += r.w;
        }
        *reinterpret_cast<float4*>(Co + m * N + nc) = o;
      }
    }
  }
}

// ---------------------------------------------------------------------------
// Flash attention, fp32, GEMM-style. One block = 64 q-rows of one (b,h).
// 256 threads. Per 64-key tile: S=QK^T (micro-tiled outer product on LDS
// Q^T/K^T), online softmax (4 threads/row), O+=P·V (micro-tiled, P^T in LDS).
// K and V share one LDS buffer (K is dead after S-compute). Static LDS 53KB.
// ---------------------------------------------------------------------------
template <bool CAUSAL>
__global__ __launch_bounds__(256) void attn_kernel(
    const float* __restrict__ Qb, const float* __restrict__ Kb,
    const float* __restrict__ Vb, float* __restrict__ Ob,
    int Tk, int qRow, int kRow, long qBatch, long kBatch) {
  __shared__ float Qst[64][68];   // Q^T: Qst[d][r]
  __shared__ float KVs[64][68];   // K^T: KVs[d][s] during S; V: KVs[s][d] during PV
  __shared__ float Ps[64][68];    // P^T: Ps[s][r]
  __shared__ float mrow[64], lrow[64], srow[64];

  const int bh = blockIdx.y;
  const int b = bh >> 4, h = bh & 15;
  const int qt = blockIdx.x;
  const int tid = threadIdx.x;
  const int tx = tid & 15, ty = tid >> 4;
  const int lr = tid >> 2, lc = tid & 3;  // staging/softmax: row 0..63, quarter 0..3

  // --- stage Q transposed (once) ---
  {
    const float* qp = Qb + (size_t)b * qBatch + (size_t)(qt * 64 + lr) * qRow + h * D_ + lc * 16;
#pragma unroll
    for (int jj = 0; jj < 4; ++jj) {
      const float4 q4 = reinterpret_cast<const float4*>(qp)[jj];
      const int d = lc * 16 + jj * 4;
      Qst[d + 0][lr] = q4.x; Qst[d + 1][lr] = q4.y;
      Qst[d + 2][lr] = q4.z; Qst[d + 3][lr] = q4.w;
    }
    if (tid < 64) { mrow[tid] = -INFINITY; lrow[tid] = 0.f; }
  }

  float o[4][4] = {{0.f}};
  const int nt = CAUSAL ? (qt + 1) : (Tk >> 6);

  for (int kt = 0; kt < nt; ++kt) {
    __syncthreads();  // prev PV reads of KVs/Ps done; Q staged (first iter)
    // --- stage K^T ---
    {
      const float* kp = Kb + (size_t)b * kBatch + (size_t)(kt * 64 + lr) * kRow + h * D_ + lc * 16;
#pragma unroll
      for (int jj = 0; jj < 4; ++jj) {
        const float4 k4 = reinterpret_cast<const float4*>(kp)[jj];
        const int d = lc * 16 + jj * 4;
        KVs[d + 0][lr] = k4.x; KVs[d + 1][lr] = k4.y;
        KVs[d + 2][lr] = k4.z; KVs[d + 3][lr] = k4.w;
      }
    }
    __syncthreads();

    // --- S = (Q K^T) * scale ; rows ty*4+i, keys tx*4+j ; write P^T ---
    {
      float sacc[4][4] = {{0.f}};
#pragma unroll
      for (int d = 0; d < 64; ++d) {
        const float4 qa = *reinterpret_cast<const float4*>(&Qst[d][ty * 4]);
        const float4 kb = *reinterpret_cast<const float4*>(&KVs[d][tx * 4]);
        fma4x4(sacc, qa, kb);
      }
#pragma unroll
      for (int i = 0; i < 4; ++i)
#pragma unroll
        for (int j = 0; j < 4; ++j)
          Ps[tx * 4 + j][ty * 4 + i] = sacc[i][j] * 0.125f;  // 1/sqrt(64)
    }
    __syncthreads();  // K reads done, P^T visible

    // --- stage V (overwrites K buffer) + online softmax (independent) ---
    {
      const float* vp = Vb + (size_t)b * kBatch + (size_t)(kt * 64 + lr) * kRow + h * D_ + lc * 16;
      float4 v4[4];
#pragma unroll
      for (int jj = 0; jj < 4; ++jj) v4[jj] = reinterpret_cast<const float4*>(vp)[jj];

      // softmax: thread handles row lr, keys lc*16..lc*16+15
      const int rg = qt * 64 + lr;
      float sc[16];
      float tmax = -INFINITY;
#pragma unroll
      for (int kk = 0; kk < 16; ++kk) {
        const int s = lc * 16 + kk;
        float v = Ps[s][lr];
        const bool valid = (!CAUSAL) || ((kt * 64 + s) <= rg);
        v = valid ? v : -INFINITY;
        sc[kk] = v;
        tmax = fmaxf(tmax, v);
      }
      tmax = fmaxf(tmax, __shfl_xor(tmax, 1));
      tmax = fmaxf(tmax, __shfl_xor(tmax, 2));
      const float mold = mrow[lr];
      const float mnew = fmaxf(mold, tmax);
      float psum = 0.f;
#pragma unroll
      for (int kk = 0; kk < 16; ++kk) {
        const int s = lc * 16 + kk;
        const float p = (sc[kk] == -INFINITY) ? 0.f : __expf(sc[kk] - mnew);
        Ps[s][lr] = p;
        psum += p;
      }
      psum += __shfl_xor(psum, 1);
      psum += __shfl_xor(psum, 2);
      if (lc == 0) {
        const float scl = (mold == -INFINITY) ? 0.f : __expf(mold - mnew);
        lrow[lr] = lrow[lr] * scl + psum;
        mrow[lr] = mnew;
        srow[lr] = scl;
      }

      // V writes (after loads returned; softmax hid the latency)
#pragma unroll
      for (int jj = 0; jj < 4; ++jj)
        *reinterpret_cast<float4*>(&KVs[lr][lc * 16 + jj * 4]) = v4[jj];
    }
    __syncthreads();  // V staged, P + srow final

    // --- O = O*scl + P·V ; rows ty*4+i, dims tx*4+j ---
    {
      float scl_i[4];
#pragma unroll
      for (int i = 0; i < 4; ++i) scl_i[i] = srow[ty * 4 + i];
#pragma unroll
      for (int i = 0; i < 4; ++i)
#pragma unroll
        for (int j = 0; j < 4; ++j) o[i][j] *= scl_i[i];
#pragma unroll
      for (int s = 0; s < 64; ++s) {
        const float4 pa = *reinterpret_cast<const float4*>(&Ps[s][ty * 4]);
        const float4 vb = *reinterpret_cast<const float4*>(&KVs[s][tx * 4]);
        fma4x4(o, pa, vb);
      }
    }
  }

  // --- epilogue: normalize and write merged-heads output ---
#pragma unroll
  for (int i = 0; i < 4; ++i) {
    const int r = ty * 4 + i;
    const float linv = 1.0f / lrow[r];
    const size_t rg = (size_t)(qt * 64 + r);
    float4 o4;
    o4.x = o[i][0] * linv; o4.y = o[i][1] * linv;
    o4.z = o[i][2] * linv; o4.w = o[i][3] * linv;
    *reinterpret_cast<float4*>(Ob + (size_t)b * T_ * C_ + rg * C_ + h * D_ + tx * 4) = o4;
  }
}

// ---------------------------------------------------------------------------
// Launch: d_out is the running residual x.  Workspace layout:
//   bufH   : 8192*1024 f32 (32 MB)  — LN outputs / attention outputs
//   bufBig : 8192*4096 f32 (128 MB) — qkv / q+kv / ff1
// Peak ws = 160 MB.
// ---------------------------------------------------------------------------
extern "C" void kernel_launch(void* const* d_in, const int* in_sizes, int n_in,
                              void* d_out, int out_size, void* d_ws, size_t ws_size,
                              hipStream_t stream) {
  const float* x    = (const float*)d_in[0];
  const float* ctx  = (const float*)d_in[1];
  const float* ln1g = (const float*)d_in[2];
  const float* ln1b = (const float*)d_in[3];
  const float* ln2g = (const float*)d_in[4];
  const float* ln2b = (const float*)d_in[5];
  const float* ln3g = (const float*)d_in[6];
  const float* ln3b = (const float*)d_in[7];
  const float* Wqkv = (const float*)d_in[8];
  const float* Wsp  = (const float*)d_in[9];
  const float* bsp  = (const float*)d_in[10];
  const float* Wq   = (const float*)d_in[11];
  const float* Wkv  = (const float*)d_in[12];
  const float* Wcp  = (const float*)d_in[13];
  const float* bcp  = (const float*)d_in[14];
  const float* Wf1  = (const float*)d_in[15];
  const float* bf1  = (const float*)d_in[16];
  const float* Wf2  = (const float*)d_in[17];
  const float* bf2  = (const float*)d_in[18];
  float* out = (float*)d_out;

  float* bufH   = (float*)d_ws;                      // 8192*1024 floats
  float* bufBig = bufH + (size_t)8192 * 1024;        // 8192*4096 floats
  float* bufKV  = bufBig + (size_t)8192 * 1024;      // kv region (after q)

  const int M = B_ * T_;  // 8192
  const dim3 blk(256);

  // --- self-attention ---
  ln_kernel<<<M, blk, 0, stream>>>(x, ln1g, ln1b, bufH);
  gemm_kernel<EPI_NONE><<<dim3(3 * C_ / 128, M / 128), blk, 0, stream>>>(
      bufH, Wqkv, nullptr, nullptr, bufBig, M, 3 * C_, C_);
  attn_kernel<true><<<dim3(T_ / 64, B_ * H_), blk, 0, stream>>>(
      bufBig, bufBig + C_, bufBig + 2 * C_, bufH,
      T_, 3 * C_, 3 * C_, (long)T_ * 3 * C_, (long)T_ * 3 * C_);
  gemm_kernel<EPI_BIAS_RESID><<<dim3(C_ / 128, M / 128), blk, 0, stream>>>(
      bufH, Wsp, bsp, x, out, M, C_, C_);

  // --- cross-attention ---
  ln_kernel<<<M, blk, 0, stream>>>(out, ln2g, ln2b, bufH);
  gemm_kernel<EPI_NONE><<<dim3(C_ / 128, M / 128), blk, 0, stream>>>(
      bufH, Wq, nullptr, nullptr, bufBig, M, C_, C_);
  gemm_kernel<EPI_NONE><<<dim3(2 * C_ / 128, (B_ * S_) / 128), blk, 0, stream>>>(
      ctx, Wkv, nullptr, nullptr, bufKV, B_ * S_, 2 * C_, C_);
  attn_kernel<false><<<dim3(T_ / 64, B_ * H_), blk, 0, stream>>>(
      bufBig, bufKV, bufKV + C_, bufH,
      S_, C_, 2 * C_, (long)T_ * C_, (long)S_ * 2 * C_);
  gemm_kernel<EPI_BIAS_RESID><<<dim3(C_ / 128, M / 128), blk, 0, stream>>>(
      bufH, Wcp, bcp, out, out, M, C_, C_);

  // --- FFN ---
  ln_kernel<<<M, blk, 0, stream>>>(out, ln3g, ln3b, bufH);
  gemm_kernel<EPI_BIAS_GELU><<<dim3(F_ / 128, M / 128), blk, 0, stream>>>(
      bufH, Wf1, bf1, nullptr, bufBig, M, F_, C_);
  gemm_kernel<EPI_BIAS_RESID><<<dim3(C_ / 128, M / 128), blk, 0, stream>>>(
      bufBig, Wf2, bf2, out, out, M, C_, F_);
}

// Round 4
// 740.047 us; speedup vs baseline: 4.9517x; 4.9517x over previous
//
#include <hip/hip_runtime.h>
#include <math.h>

constexpr int B_ = 8, T_ = 1024, S_ = 256, C_ = 1024, H_ = 16, F_ = 4096, D_ = 64;

typedef __attribute__((ext_vector_type(8))) short bf16x8;      // 8 bf16 (4 VGPR) MFMA frag
typedef __attribute__((ext_vector_type(8))) unsigned short ushort8;
typedef __attribute__((ext_vector_type(4))) unsigned short ushort4v;
typedef __attribute__((ext_vector_type(4))) float f32x4;

__device__ __forceinline__ unsigned short f2bf(float f) {  // RN float->bf16
  union { float f; unsigned u; } c; c.f = f;
  unsigned u = c.u;
  u += 0x7FFFu + ((u >> 16) & 1u);
  return (unsigned short)(u >> 16);
}

// async global->LDS, 16B per lane. LDS dest must be wave-uniform base; HW adds lane*16.
// AS casts via integer round-trip (LDS aperture: offset lives in low 32 bits).
__device__ __forceinline__ void gload16(const void* g, void* l) {
  typedef __attribute__((address_space(3))) unsigned int lds_u32;
  typedef __attribute__((address_space(1))) const unsigned int glb_u32;
  __builtin_amdgcn_global_load_lds((glb_u32*)(size_t)g,
                                   (lds_u32*)(unsigned)(size_t)l, 16, 0, 0);
}

__device__ __forceinline__ float gelu_exact(float v) {
  return 0.5f * v * (1.0f + erff(v * 0.70710678118654752440f));
}

// ---------------------------------------------------------------------------
// LayerNorm fp32 -> bf16 out. One block/row, 256 threads, float4/thread.
// ---------------------------------------------------------------------------
__global__ __launch_bounds__(256) void ln_kernel(
    const float* __restrict__ x, const float* __restrict__ g,
    const float* __restrict__ b, unsigned short* __restrict__ out) {
  const int row = blockIdx.x;
  const int t = threadIdx.x;
  const float4 v = reinterpret_cast<const float4*>(x + (size_t)row * C_)[t];
  float sum = v.x + v.y + v.z + v.w;
  float ss  = v.x * v.x + v.y * v.y + v.z * v.z + v.w * v.w;
#pragma unroll
  for (int o = 1; o < 64; o <<= 1) {
    sum += __shfl_xor(sum, o);
    ss  += __shfl_xor(ss, o);
  }
  __shared__ float s1[4], s2[4];
  const int wid = t >> 6;
  if ((t & 63) == 0) { s1[wid] = sum; s2[wid] = ss; }
  __syncthreads();
  sum = s1[0] + s1[1] + s1[2] + s1[3];
  ss  = s2[0] + s2[1] + s2[2] + s2[3];
  const float inv = 1.0f / (float)C_;
  const float mu  = sum * inv;
  const float var = ss * inv - mu * mu;
  const float rstd = rsqrtf(var + 1e-5f);
  const float4 gg = reinterpret_cast<const float4*>(g)[t];
  const float4 bb = reinterpret_cast<const float4*>(b)[t];
  ushort4v o4;
  o4[0] = f2bf((v.x - mu) * rstd * gg.x + bb.x);
  o4[1] = f2bf((v.y - mu) * rstd * gg.y + bb.y);
  o4[2] = f2bf((v.z - mu) * rstd * gg.z + bb.z);
  o4[3] = f2bf((v.w - mu) * rstd * gg.w + bb.w);
  *reinterpret_cast<ushort4v*>(out + (size_t)row * C_ + t * 4) = o4;
}

// ---------------------------------------------------------------------------
// Weight convert+transpose: fp32 [K][N] -> bf16 [N][K]. 64x64 tiles.
// ---------------------------------------------------------------------------
__global__ __launch_bounds__(256) void wconvT_kernel(
    const float* __restrict__ W, unsigned short* __restrict__ Wt, int K, int N) {
  __shared__ unsigned short Lt[64][72];  // [n][k]
  const int tid = threadIdx.x;
  const int n0 = blockIdx.x * 64, k0 = blockIdx.y * 64;
#pragma unroll
  for (int j = 0; j < 4; ++j) {
    const int kk = j * 16 + (tid >> 4);
    const float4 v = *reinterpret_cast<const float4*>(W + (size_t)(k0 + kk) * N + n0 + (tid & 15) * 4);
    const int nn = (tid & 15) * 4;
    Lt[nn + 0][kk] = f2bf(v.x);
    Lt[nn + 1][kk] = f2bf(v.y);
    Lt[nn + 2][kk] = f2bf(v.z);
    Lt[nn + 3][kk] = f2bf(v.w);
  }
  __syncthreads();
  const int rr = tid >> 3, ck = tid & 7;
#pragma unroll
  for (int j = 0; j < 2; ++j) {
    const int n = j * 32 + rr;
    *reinterpret_cast<ushort8*>(Wt + (size_t)(n0 + n) * K + k0 + ck * 8) =
        *reinterpret_cast<const ushort8*>(&Lt[n][ck * 8]);
  }
}

// fp32 -> bf16 elementwise (ctx). 8 elems/thread.
__global__ __launch_bounds__(256) void f2bf_kernel(
    const float* __restrict__ in, unsigned short* __restrict__ o, int n8) {
  const int i = blockIdx.x * 256 + threadIdx.x;
  if (i < n8) {
    const float4 a = *reinterpret_cast<const float4*>(in + (size_t)i * 8);
    const float4 b = *reinterpret_cast<const float4*>(in + (size_t)i * 8 + 4);
    ushort8 r;
    r[0] = f2bf(a.x); r[1] = f2bf(a.y); r[2] = f2bf(a.z); r[3] = f2bf(a.w);
    r[4] = f2bf(b.x); r[5] = f2bf(b.y); r[6] = f2bf(b.z); r[7] = f2bf(b.w);
    *reinterpret_cast<ushort8*>(o + (size_t)i * 8) = r;
  }
}

// ---------------------------------------------------------------------------
// V transpose per (b,h): bf16 [Ts][64] (row stride ldsrc) -> bf16 [bh][64][Ts]
// ---------------------------------------------------------------------------
__global__ __launch_bounds__(256) void vtrans_kernel(
    const unsigned short* __restrict__ src, unsigned short* __restrict__ dst,
    int ldsrc, int Ts) {
  __shared__ unsigned short Lt[64][72];  // [d][t]
  const int tid = threadIdx.x;
  const int bh = blockIdx.y, b = bh >> 4, h = bh & 15;
  const int t0 = blockIdx.x * 64;
  const int rr = tid >> 3, ck = tid & 7;
#pragma unroll
  for (int j = 0; j < 2; ++j) {
    const int t = j * 32 + rr;
    const ushort8 v = *reinterpret_cast<const ushort8*>(
        src + (size_t)(b * Ts + t0 + t) * ldsrc + h * 64 + ck * 8);
#pragma unroll
    for (int e = 0; e < 8; ++e) Lt[ck * 8 + e][t] = v[e];
  }
  __syncthreads();
#pragma unroll
  for (int j = 0; j < 2; ++j) {
    const int d = j * 32 + rr;
    *reinterpret_cast<ushort8*>(dst + ((size_t)bh * 64 + d) * Ts + t0 + ck * 8) =
        *reinterpret_cast<const ushort8*>(&Lt[d][ck * 8]);
  }
}

// ---------------------------------------------------------------------------
// bf16 MFMA GEMM (m97 structure): C[M,N] = A[M,K] @ Bt[N,K]^T (+epi)
// 128x128 tile, BK=32, 4 waves (each 64x64 = 4x4 frags of 16x16x32).
// global_load_lds(16B) staging; K-slot XOR swizzle kb^((row>>1)&3) -> <=2-way.
// EPI_NONE / BIAS_GELU write bf16; BIAS_RESID writes fp32 (+bias+resid).
// ---------------------------------------------------------------------------
enum { EPI_NONE = 0, EPI_BIAS_RESID = 1, EPI_BIAS_GELU = 2 };

template <int EPI>
__global__ __launch_bounds__(256) void gemm_bf16(
    const unsigned short* __restrict__ A, const unsigned short* __restrict__ Bt,
    const float* __restrict__ bias, const float* __restrict__ resid,
    void* __restrict__ Cout, int M, int N, int K) {
  __shared__ unsigned short As[128 * 32];
  __shared__ unsigned short Bs[128 * 32];
  const int tid = threadIdx.x;
  const int w = tid >> 6, lane = tid & 63;
  const int ql = lane & 15, g = lane >> 4;
  const int bm = blockIdx.y * 128, bn = blockIdx.x * 128;
  const int wr = w >> 1, wc = w & 1;

  f32x4 acc[4][4] = {};

  const int srow16 = lane >> 2;  // 0..15 (staging row within 16-row group)
  const int skb = lane & 3;      // linear dest k-slot

  for (int k0 = 0; k0 < K; k0 += 32) {
#pragma unroll
    for (int i = 0; i < 2; ++i) {
      const int row = i * 64 + w * 16 + srow16;
      const int kb = skb ^ ((row >> 1) & 3);  // inverse-swizzled source
      gload16(A + (size_t)(bm + row) * K + k0 + kb * 8,
              (void*)(As + (i * 64 + w * 16) * 32));
      gload16(Bt + (size_t)(bn + row) * K + k0 + kb * 8,
              (void*)(Bs + (i * 64 + w * 16) * 32));
    }
    __syncthreads();  // drains vmcnt -> LDS writes visible
    bf16x8 af[4], bfr[4];
#pragma unroll
    for (int f = 0; f < 4; ++f) {
      const int ra = wr * 64 + f * 16 + ql;
      af[f] = *reinterpret_cast<const bf16x8*>(As + ra * 32 + (g ^ ((ra >> 1) & 3)) * 8);
      const int rb = wc * 64 + f * 16 + ql;
      bfr[f] = *reinterpret_cast<const bf16x8*>(Bs + rb * 32 + (g ^ ((rb >> 1) & 3)) * 8);
    }
#pragma unroll
    for (int mf = 0; mf < 4; ++mf)
#pragma unroll
      for (int nf = 0; nf < 4; ++nf)
        acc[mf][nf] = __builtin_amdgcn_mfma_f32_16x16x32_bf16(af[mf], bfr[nf], acc[mf][nf], 0, 0, 0);
    __syncthreads();
  }

  // epilogue: lane holds C[m = bm+wr*64+mf*16+g*4+r][n = bn+wc*64+nf*16+ql]
  float b4[4];
  if (EPI != EPI_NONE) {
#pragma unroll
    for (int nf = 0; nf < 4; ++nf) b4[nf] = bias[bn + wc * 64 + nf * 16 + ql];
  }
#pragma unroll
  for (int mf = 0; mf < 4; ++mf) {
#pragma unroll
    for (int r = 0; r < 4; ++r) {
      const size_t m = (size_t)(bm + wr * 64 + mf * 16 + g * 4 + r);
      const int ncol = bn + wc * 64 + ql;
      if (EPI == EPI_BIAS_RESID) {
        float* op = (float*)Cout + m * N + ncol;
        const float* rp = resid + m * N + ncol;
#pragma unroll
        for (int nf = 0; nf < 4; ++nf)
          op[nf * 16] = acc[mf][nf][r] + b4[nf] + rp[nf * 16];
      } else {
        unsigned short* op = (unsigned short*)Cout + m * N + ncol;
#pragma unroll
        for (int nf = 0; nf < 4; ++nf) {
          float v = acc[mf][nf][r];
          if (EPI == EPI_BIAS_GELU) v = gelu_exact(v + b4[nf]);
          op[nf * 16] = f2bf(v);
        }
      }
    }
  }
}

// ---------------------------------------------------------------------------
// MFMA flash attention. Block = 64 q-rows of one (b,h), 4 waves (16 q each).
// Swapped S^T = K*Q^T (lane owns one q); online softmax (2 shuffles);
// P -> LDS bf16; O^T = V^T * P^T with V pre-transposed in global (Vt).
// LDS: Ks 8K + Vs 8K + Pt 9.2K. All frag reads XOR-swizzled (<=2-way).
// ---------------------------------------------------------------------------
template <bool CAUSAL>
__global__ __launch_bounds__(256) void attn_mfma(
    const unsigned short* __restrict__ Qb, const unsigned short* __restrict__ Kb,
    const unsigned short* __restrict__ Vt, unsigned short* __restrict__ Ob,
    int Tk, int ldq, int ldk) {
  __shared__ unsigned short Ks[64 * 64];   // [key][d], swizzled slots
  __shared__ unsigned short Vs[64 * 64];   // [d][s],  swizzled slots
  __shared__ unsigned short Pt[64][72];    // [q][s], padded (2-way)
  const int tid = threadIdx.x;
  const int w = tid >> 6, lane = tid & 63;
  const int ql = lane & 15, g = lane >> 4;
  const int bh = blockIdx.y, b = bh >> 4, h = bh & 15;
  const int qt = blockIdx.x;
  const int qrow = w * 16 + ql;        // q within block
  const int qg = qt * 64 + qrow;       // q within sequence

  bf16x8 qf0, qf1;
  {
    const unsigned short* qr = Qb + (size_t)(b * T_ + qg) * ldq + h * 64;
    qf0 = *reinterpret_cast<const bf16x8*>(qr + g * 8);
    qf1 = *reinterpret_cast<const bf16x8*>(qr + 32 + g * 8);
  }
  float m_run = -INFINITY, l_run = 0.f;
  f32x4 oacc[4] = {};

  const int nt = CAUSAL ? (qt + 1) : (Tk >> 6);
  const int srow = lane >> 3, skb = lane & 7;

  for (int kt = 0; kt < nt; ++kt) {
    // --- stage K tile [64 keys][64 d] and V^T tile [64 d][64 s] ---
#pragma unroll
    for (int i = 0; i < 2; ++i) {
      const int rloc = i * 32 + w * 8 + srow;
      const int kb = skb ^ (rloc & 7);  // inverse-swizzled source slot
      gload16(Kb + (size_t)(b * Tk + kt * 64 + rloc) * ldk + h * 64 + kb * 8,
              (void*)(Ks + (i * 32 + w * 8) * 64));
      gload16(Vt + ((size_t)bh * 64 + rloc) * Tk + kt * 64 + kb * 8,
              (void*)(Vs + (i * 32 + w * 8) * 64));
    }
    __syncthreads();

    // --- S^T = K * Q^T : D[key][q], wave's 16 q columns ---
    f32x4 sacc[4] = {};
#pragma unroll
    for (int kf = 0; kf < 4; ++kf) {
      const int kr = kf * 16 + ql;
      const int sw = ql & 7;
      const bf16x8 k0v = *reinterpret_cast<const bf16x8*>(Ks + kr * 64 + ((0 + g) ^ sw) * 8);
      const bf16x8 k1v = *reinterpret_cast<const bf16x8*>(Ks + kr * 64 + ((4 + g) ^ sw) * 8);
      sacc[kf] = __builtin_amdgcn_mfma_f32_16x16x32_bf16(k0v, qf0, sacc[kf], 0, 0, 0);
      sacc[kf] = __builtin_amdgcn_mfma_f32_16x16x32_bf16(k1v, qf1, sacc[kf], 0, 0, 0);
    }

    // --- online softmax: lane's 16 scores all belong to q = qrow ---
    float sc[4][4];
    float tmax = -INFINITY;
#pragma unroll
    for (int kf = 0; kf < 4; ++kf)
#pragma unroll
      for (int r = 0; r < 4; ++r) {
        float v = sacc[kf][r] * 0.125f;  // 1/sqrt(64)
        if (CAUSAL) {
          const int key = kt * 64 + kf * 16 + g * 4 + r;
          if (key > qg) v = -INFINITY;
        }
        sc[kf][r] = v;
        tmax = fmaxf(tmax, v);
      }
    tmax = fmaxf(tmax, __shfl_xor(tmax, 16));
    tmax = fmaxf(tmax, __shfl_xor(tmax, 32));
    const float mnew = fmaxf(m_run, tmax);
    const float scl = __expf(m_run - mnew);  // 0 on first tile (exp(-inf))
    float psum = 0.f;
    unsigned short pb[4][4];
#pragma unroll
    for (int kf = 0; kf < 4; ++kf)
#pragma unroll
      for (int r = 0; r < 4; ++r) {
        const float p = __expf(sc[kf][r] - mnew);  // masked -> exp(-inf) = 0
        psum += p;
        pb[kf][r] = f2bf(p);
      }
    psum += __shfl_xor(psum, 16);
    psum += __shfl_xor(psum, 32);
    l_run = l_run * scl + psum;
    m_run = mnew;
#pragma unroll
    for (int df = 0; df < 4; ++df)
#pragma unroll
      for (int r = 0; r < 4; ++r) oacc[df][r] *= scl;
#pragma unroll
    for (int kf = 0; kf < 4; ++kf) {
      ushort4v p4; p4[0] = pb[kf][0]; p4[1] = pb[kf][1]; p4[2] = pb[kf][2]; p4[3] = pb[kf][3];
      *reinterpret_cast<ushort4v*>(&Pt[qrow][kf * 16 + g * 4]) = p4;
    }
    __syncthreads();  // Pt visible; Ks reads done

    // --- O^T += V^T * P^T : D[d][q] ---
    const bf16x8 p0 = *reinterpret_cast<const bf16x8*>(&Pt[qrow][g * 8]);
    const bf16x8 p1 = *reinterpret_cast<const bf16x8*>(&Pt[qrow][32 + g * 8]);
#pragma unroll
    for (int df = 0; df < 4; ++df) {
      const int vr = df * 16 + ql;
      const int sw = ql & 7;
      const bf16x8 v0 = *reinterpret_cast<const bf16x8*>(Vs + vr * 64 + ((0 + g) ^ sw) * 8);
      const bf16x8 v1 = *reinterpret_cast<const bf16x8*>(Vs + vr * 64 + ((4 + g) ^ sw) * 8);
      oacc[df] = __builtin_amdgcn_mfma_f32_16x16x32_bf16(v0, p0, oacc[df], 0, 0, 0);
      oacc[df] = __builtin_amdgcn_mfma_f32_16x16x32_bf16(v1, p1, oacc[df], 0, 0, 0);
    }
    __syncthreads();  // Vs/Pt reads done before next stage
  }

  const float linv = 1.0f / l_run;
  unsigned short* orow = Ob + (size_t)(b * T_ + qg) * C_ + h * 64;
#pragma unroll
  for (int df = 0; df < 4; ++df)
#pragma unroll
    for (int r = 0; r < 4; ++r)
      orow[df * 16 + g * 4 + r] = f2bf(oacc[df][r] * linv);
}

// ---------------------------------------------------------------------------
// Launch. Workspace layout (132 MB total):
//   [0,32M)   bf16 transposed weights
//   [32,36M)  ctx bf16
//   [36,52M)  lnout bf16   [52,68M) attno bf16
//   [68,132M) Region A: qkv+VtS | qbuf+kv+VtC | ff1out  (sequential reuse)
// ---------------------------------------------------------------------------
extern "C" void kernel_launch(void* const* d_in, const int* in_sizes, int n_in,
                              void* d_out, int out_size, void* d_ws, size_t ws_size,
                              hipStream_t stream) {
  const float* x    = (const float*)d_in[0];
  const float* ctx  = (const float*)d_in[1];
  const float* ln1g = (const float*)d_in[2];
  const float* ln1b = (const float*)d_in[3];
  const float* ln2g = (const float*)d_in[4];
  const float* ln2b = (const float*)d_in[5];
  const float* ln3g = (const float*)d_in[6];
  const float* ln3b = (const float*)d_in[7];
  const float* Wqkv = (const float*)d_in[8];
  const float* Wsp  = (const float*)d_in[9];
  const float* bsp  = (const float*)d_in[10];
  const float* Wq   = (const float*)d_in[11];
  const float* Wkv  = (const float*)d_in[12];
  const float* Wcp  = (const float*)d_in[13];
  const float* bcp  = (const float*)d_in[14];
  const float* Wf1  = (const float*)d_in[15];
  const float* bf1  = (const float*)d_in[16];
  const float* Wf2  = (const float*)d_in[17];
  const float* bf2  = (const float*)d_in[18];
  float* out = (float*)d_out;

  char* wsb = (char*)d_ws;
  unsigned short* WqkvT = (unsigned short*)(wsb + 0);          // 6 MB
  unsigned short* WspT  = (unsigned short*)(wsb + 6291456);    // 2 MB
  unsigned short* WqT   = (unsigned short*)(wsb + 8388608);    // 2 MB
  unsigned short* WkvT  = (unsigned short*)(wsb + 10485760);   // 4 MB
  unsigned short* WcpT  = (unsigned short*)(wsb + 14680064);   // 2 MB
  unsigned short* Wf1T  = (unsigned short*)(wsb + 16777216);   // 8 MB
  unsigned short* Wf2T  = (unsigned short*)(wsb + 25165824);   // 8 MB
  unsigned short* ctxb  = (unsigned short*)(wsb + 33554432);   // 4 MB
  unsigned short* lnout = (unsigned short*)(wsb + 37748736);   // 16 MB
  unsigned short* attno = (unsigned short*)(wsb + 54525952);   // 16 MB
  char* regA = wsb + 71303168;                                  // 64 MB
  unsigned short* qkvb = (unsigned short*)regA;                // 48 MB
  unsigned short* VtS  = (unsigned short*)(regA + 50331648);   // 16 MB
  unsigned short* qbuf = (unsigned short*)regA;                // 16 MB
  unsigned short* kvb  = (unsigned short*)(regA + 16777216);   // 8 MB
  unsigned short* VtC  = (unsigned short*)(regA + 25165824);   // 4 MB
  unsigned short* ff1o = (unsigned short*)regA;                // 64 MB

  const dim3 blk(256);

  // --- weight/ctx conversion (every call; ws is re-poisoned by harness) ---
  wconvT_kernel<<<dim3(48, 16), blk, 0, stream>>>(Wqkv, WqkvT, 1024, 3072);
  wconvT_kernel<<<dim3(16, 16), blk, 0, stream>>>(Wsp, WspT, 1024, 1024);
  wconvT_kernel<<<dim3(16, 16), blk, 0, stream>>>(Wq, WqT, 1024, 1024);
  wconvT_kernel<<<dim3(32, 16), blk, 0, stream>>>(Wkv, WkvT, 1024, 2048);
  wconvT_kernel<<<dim3(16, 16), blk, 0, stream>>>(Wcp, WcpT, 1024, 1024);
  wconvT_kernel<<<dim3(64, 16), blk, 0, stream>>>(Wf1, Wf1T, 1024, 4096);
  wconvT_kernel<<<dim3(16, 64), blk, 0, stream>>>(Wf2, Wf2T, 4096, 1024);
  f2bf_kernel<<<1024, blk, 0, stream>>>(ctx, ctxb, 262144);

  // --- causal self-attention ---
  ln_kernel<<<8192, blk, 0, stream>>>(x, ln1g, ln1b, lnout);
  gemm_bf16<EPI_NONE><<<dim3(24, 64), blk, 0, stream>>>(
      lnout, WqkvT, nullptr, nullptr, qkvb, 8192, 3072, 1024);
  vtrans_kernel<<<dim3(16, 128), blk, 0, stream>>>(qkvb + 2048, VtS, 3072, 1024);
  attn_mfma<true><<<dim3(16, 128), blk, 0, stream>>>(
      qkvb, qkvb + 1024, VtS, attno, 1024, 3072, 3072);
  gemm_bf16<EPI_BIAS_RESID><<<dim3(8, 64), blk, 0, stream>>>(
      attno, WspT, bsp, x, out, 8192, 1024, 1024);

  // --- cross-attention ---
  ln_kernel<<<8192, blk, 0, stream>>>(out, ln2g, ln2b, lnout);
  gemm_bf16<EPI_NONE><<<dim3(8, 64), blk, 0, stream>>>(
      lnout, WqT, nullptr, nullptr, qbuf, 8192, 1024, 1024);
  gemm_bf16<EPI_NONE><<<dim3(16, 16), blk, 0, stream>>>(
      ctxb, WkvT, nullptr, nullptr, kvb, 2048, 2048, 1024);
  vtrans_kernel<<<dim3(4, 128), blk, 0, stream>>>(kvb + 1024, VtC, 2048, 256);
  attn_mfma<false><<<dim3(16, 128), blk, 0, stream>>>(
      qbuf, kvb, VtC, attno, 256, 1024, 2048);
  gemm_bf16<EPI_BIAS_RESID><<<dim3(8, 64), blk, 0, stream>>>(
      attno, WcpT, bcp, out, out, 8192, 1024, 1024);

  // --- FFN ---
  ln_kernel<<<8192, blk, 0, stream>>>(out, ln3g, ln3b, lnout);
  gemm_bf16<EPI_BIAS_GELU><<<dim3(32, 64), blk, 0, stream>>>(
      lnout, Wf1T, bf1, nullptr, ff1o, 8192, 4096, 1024);
  gemm_bf16<EPI_BIAS_RESID><<<dim3(8, 64), blk, 0, stream>>>(
      ff1o, Wf2T, bf2, out, out, 8192, 1024, 4096);
}

// Round 6
// 693.541 us; speedup vs baseline: 5.2838x; 1.0671x over previous
//
#include <hip/hip_runtime.h>
#include <math.h>

constexpr int B_ = 8, T_ = 1024, S_ = 256, C_ = 1024, H_ = 16, F_ = 4096, D_ = 64;

typedef __attribute__((ext_vector_type(8))) short bf16x8;      // 8 bf16 (4 VGPR) MFMA frag
typedef __attribute__((ext_vector_type(8))) unsigned short ushort8;
typedef __attribute__((ext_vector_type(4))) unsigned short ushort4v;
typedef __attribute__((ext_vector_type(4))) float f32x4;

__device__ __forceinline__ unsigned short f2bf(float f) {  // RN float->bf16
  union { float f; unsigned u; } c; c.f = f;
  unsigned u = c.u;
  u += 0x7FFFu + ((u >> 16) & 1u);
  return (unsigned short)(u >> 16);
}

// async global->LDS, 16B per lane. LDS dest must be wave-uniform base; HW adds lane*16.
__device__ __forceinline__ void gload16(const void* g, void* l) {
  typedef __attribute__((address_space(3))) unsigned int lds_u32;
  typedef __attribute__((address_space(1))) const unsigned int glb_u32;
  __builtin_amdgcn_global_load_lds((glb_u32*)(size_t)g,
                                   (lds_u32*)(unsigned)(size_t)l, 16, 0, 0);
}

// tanh-GELU via one exp: gelu(x) = x * sigmoid(1.5957691x(1+0.044715x^2)).
// |err vs exact erf-GELU| ~1e-3 on h; after W_ff2 contraction ~1e-3 abs.
__device__ __forceinline__ float gelu_fast(float v) {
  return v / (1.0f + __expf(-1.5957691216057308f * v * (1.0f + 0.044715f * v * v)));
}

// ---------------------------------------------------------------------------
// LayerNorm fp32 -> bf16 out. One block/row, 256 threads, float4/thread.
// jnp.var is biased (/N); eps inside rsqrt — matches reference.
// ---------------------------------------------------------------------------
__global__ __launch_bounds__(256) void ln_kernel(
    const float* __restrict__ x, const float* __restrict__ g,
    const float* __restrict__ b, unsigned short* __restrict__ out) {
  const int row = blockIdx.x;
  const int t = threadIdx.x;
  const float4 v = reinterpret_cast<const float4*>(x + (size_t)row * C_)[t];
  float sum = v.x + v.y + v.z + v.w;
  float ss  = v.x * v.x + v.y * v.y + v.z * v.z + v.w * v.w;
#pragma unroll
  for (int o = 1; o < 64; o <<= 1) {
    sum += __shfl_xor(sum, o);
    ss  += __shfl_xor(ss, o);
  }
  __shared__ float s1[4], s2[4];
  const int wid = t >> 6;
  if ((t & 63) == 0) { s1[wid] = sum; s2[wid] = ss; }
  __syncthreads();
  sum = s1[0] + s1[1] + s1[2] + s1[3];
  ss  = s2[0] + s2[1] + s2[2] + s2[3];
  const float inv = 1.0f / (float)C_;
  const float mu  = sum * inv;
  const float var = ss * inv - mu * mu;
  const float rstd = rsqrtf(var + 1e-5f);
  const float4 gg = reinterpret_cast<const float4*>(g)[t];
  const float4 bb = reinterpret_cast<const float4*>(b)[t];
  ushort4v o4;
  o4[0] = f2bf((v.x - mu) * rstd * gg.x + bb.x);
  o4[1] = f2bf((v.y - mu) * rstd * gg.y + bb.y);
  o4[2] = f2bf((v.z - mu) * rstd * gg.z + bb.z);
  o4[3] = f2bf((v.w - mu) * rstd * gg.w + bb.w);
  *reinterpret_cast<ushort4v*>(out + (size_t)row * C_ + t * 4) = o4;
}

// ---------------------------------------------------------------------------
// Weight convert+transpose: fp32 [K][N] -> bf16 [N][K]. 64x64 tiles.
// ---------------------------------------------------------------------------
__global__ __launch_bounds__(256) void wconvT_kernel(
    const float* __restrict__ W, unsigned short* __restrict__ Wt, int K, int N) {
  __shared__ unsigned short Lt[64][72];  // [n][k]
  const int tid = threadIdx.x;
  const int n0 = blockIdx.x * 64, k0 = blockIdx.y * 64;
#pragma unroll
  for (int j = 0; j < 4; ++j) {
    const int kk = j * 16 + (tid >> 4);
    const float4 v = *reinterpret_cast<const float4*>(W + (size_t)(k0 + kk) * N + n0 + (tid & 15) * 4);
    const int nn = (tid & 15) * 4;
    Lt[nn + 0][kk] = f2bf(v.x);
    Lt[nn + 1][kk] = f2bf(v.y);
    Lt[nn + 2][kk] = f2bf(v.z);
    Lt[nn + 3][kk] = f2bf(v.w);
  }
  __syncthreads();
  const int rr = tid >> 3, ck = tid & 7;
#pragma unroll
  for (int j = 0; j < 2; ++j) {
    const int n = j * 32 + rr;
    *reinterpret_cast<ushort8*>(Wt + (size_t)(n0 + n) * K + k0 + ck * 8) =
        *reinterpret_cast<const ushort8*>(&Lt[n][ck * 8]);
  }
}

// fp32 -> bf16 elementwise (ctx). 8 elems/thread.
__global__ __launch_bounds__(256) void f2bf_kernel(
    const float* __restrict__ in, unsigned short* __restrict__ o, int n8) {
  const int i = blockIdx.x * 256 + threadIdx.x;
  if (i < n8) {
    const float4 a = *reinterpret_cast<const float4*>(in + (size_t)i * 8);
    const float4 b = *reinterpret_cast<const float4*>(in + (size_t)i * 8 + 4);
    ushort8 r;
    r[0] = f2bf(a.x); r[1] = f2bf(a.y); r[2] = f2bf(a.z); r[3] = f2bf(a.w);
    r[4] = f2bf(b.x); r[5] = f2bf(b.y); r[6] = f2bf(b.z); r[7] = f2bf(b.w);
    *reinterpret_cast<ushort8*>(o + (size_t)i * 8) = r;
  }
}

// ---------------------------------------------------------------------------
// V transpose per (b,h): bf16 [Ts][64] (row stride ldsrc) -> bf16 [bh][64][Ts]
// ---------------------------------------------------------------------------
__global__ __launch_bounds__(256) void vtrans_kernel(
    const unsigned short* __restrict__ src, unsigned short* __restrict__ dst,
    int ldsrc, int Ts) {
  __shared__ unsigned short Lt[64][72];  // [d][t]
  const int tid = threadIdx.x;
  const int bh = blockIdx.y, b = bh >> 4, h = bh & 15;
  const int t0 = blockIdx.x * 64;
  const int rr = tid >> 3, ck = tid & 7;
#pragma unroll
  for (int j = 0; j < 2; ++j) {
    const int t = j * 32 + rr;
    const ushort8 v = *reinterpret_cast<const ushort8*>(
        src + (size_t)(b * Ts + t0 + t) * ldsrc + h * 64 + ck * 8);
#pragma unroll
    for (int e = 0; e < 8; ++e) Lt[ck * 8 + e][t] = v[e];
  }
  __syncthreads();
#pragma unroll
  for (int j = 0; j < 2; ++j) {
    const int d = j * 32 + rr;
    *reinterpret_cast<ushort8*>(dst + ((size_t)bh * 64 + d) * Ts + t0 + ck * 8) =
        *reinterpret_cast<const ushort8*>(&Lt[d][ck * 8]);
  }
}

// ---------------------------------------------------------------------------
// bf16 MFMA GEMM, 2-phase double-buffered (T3-minimum): C = A @ Bt^T (+epi)
// 128x128 tile, BK=32, 4 waves. Prefetch next K-tile into buf^1 BEFORE
// computing buf[cur]; single __syncthreads (vmcnt+lgkm drain) per K-step.
// K-slot XOR swizzle kb^((row>>1)&3) on both stage-source and frag-read.
// ---------------------------------------------------------------------------
enum { EPI_NONE = 0, EPI_BIAS_RESID = 1, EPI_BIAS_GELU = 2 };

template <int EPI>
__global__ __launch_bounds__(256) void gemm_bf16(
    const unsigned short* __restrict__ A, const unsigned short* __restrict__ Bt,
    const float* __restrict__ bias, const float* __restrict__ resid,
    void* __restrict__ Cout, int M, int N, int K) {
  __shared__ unsigned short As[2][128 * 32];
  __shared__ unsigned short Bs[2][128 * 32];
  const int tid = threadIdx.x;
  const int w = tid >> 6, lane = tid & 63;
  const int ql = lane & 15, g = lane >> 4;
  const int bm = blockIdx.y * 128, bn = blockIdx.x * 128;
  const int wr = w >> 1, wc = w & 1;

  f32x4 acc[4][4] = {};

  const int srow16 = lane >> 2;  // 0..15 (staging row within 16-row group)
  const int skb = lane & 3;      // linear dest k-slot

  auto STAGE = [&](int bu, int k0) {
#pragma unroll
    for (int i = 0; i < 2; ++i) {
      const int row = i * 64 + w * 16 + srow16;
      const int kb = skb ^ ((row >> 1) & 3);  // inverse-swizzled source
      gload16(A + (size_t)(bm + row) * K + k0 + kb * 8,
              (void*)(As[bu] + (i * 64 + w * 16) * 32));
      gload16(Bt + (size_t)(bn + row) * K + k0 + kb * 8,
              (void*)(Bs[bu] + (i * 64 + w * 16) * 32));
    }
  };
  auto COMPUTE = [&](int bu) {
    bf16x8 af[4], bfr[4];
#pragma unroll
    for (int f = 0; f < 4; ++f) {
      const int ra = wr * 64 + f * 16 + ql;
      af[f] = *reinterpret_cast<const bf16x8*>(As[bu] + ra * 32 + (g ^ ((ra >> 1) & 3)) * 8);
      const int rb = wc * 64 + f * 16 + ql;
      bfr[f] = *reinterpret_cast<const bf16x8*>(Bs[bu] + rb * 32 + (g ^ ((rb >> 1) & 3)) * 8);
    }
#pragma unroll
    for (int mf = 0; mf < 4; ++mf)
#pragma unroll
      for (int nf = 0; nf < 4; ++nf)
        acc[mf][nf] = __builtin_amdgcn_mfma_f32_16x16x32_bf16(af[mf], bfr[nf], acc[mf][nf], 0, 0, 0);
  };

  STAGE(0, 0);
  __syncthreads();          // tile 0 resident
  int cur = 0;
  const int NT = K >> 5;
  for (int t = 0; t < NT - 1; ++t) {
    STAGE(cur ^ 1, (t + 1) * 32);  // loads fly during COMPUTE
    COMPUTE(cur);
    __syncthreads();        // drains vmcnt(0)+lgkm; prefetched tile resident
    cur ^= 1;
  }
  COMPUTE(cur);

  // epilogue: lane holds C[m = bm+wr*64+mf*16+g*4+r][n = bn+wc*64+nf*16+ql]
  float b4[4];
  if (EPI != EPI_NONE) {
#pragma unroll
    for (int nf = 0; nf < 4; ++nf) b4[nf] = bias[bn + wc * 64 + nf * 16 + ql];
  }
#pragma unroll
  for (int mf = 0; mf < 4; ++mf) {
#pragma unroll
    for (int r = 0; r < 4; ++r) {
      const size_t m = (size_t)(bm + wr * 64 + mf * 16 + g * 4 + r);
      const int ncol = bn + wc * 64 + ql;
      if (EPI == EPI_BIAS_RESID) {
        float* op = (float*)Cout + m * N + ncol;
        const float* rp = resid + m * N + ncol;
#pragma unroll
        for (int nf = 0; nf < 4; ++nf)
          op[nf * 16] = acc[mf][nf][r] + b4[nf] + rp[nf * 16];
      } else {
        unsigned short* op = (unsigned short*)Cout + m * N + ncol;
#pragma unroll
        for (int nf = 0; nf < 4; ++nf) {
          float v = acc[mf][nf][r];
          if (EPI == EPI_BIAS_GELU) v = gelu_fast(v + b4[nf]);
          op[nf * 16] = f2bf(v);
        }
      }
    }
  }
}

// ---------------------------------------------------------------------------
// MFMA flash attention, 2-phase dbuf K/V. Block = 64 q-rows of one (b,h),
// 4 waves. Prefetch next K/V tile before QK^T; mid-tile barrier is
// lgkmcnt-only (Pt dataflow is intra-wave; prefetch stays in flight);
// end-of-tile __syncthreads drains vmcnt.
// ---------------------------------------------------------------------------
template <bool CAUSAL>
__global__ __launch_bounds__(256) void attn_mfma(
    const unsigned short* __restrict__ Qb, const unsigned short* __restrict__ Kb,
    const unsigned short* __restrict__ Vt, unsigned short* __restrict__ Ob,
    int Tk, int ldq, int ldk) {
  __shared__ unsigned short Ks[2][64 * 64];   // [key][d], swizzled slots
  __shared__ unsigned short Vs[2][64 * 64];   // [d][s],  swizzled slots
  __shared__ unsigned short Pt[64][72];       // [q][s], padded (2-way)
  const int tid = threadIdx.x;
  const int w = tid >> 6, lane = tid & 63;
  const int ql = lane & 15, g = lane >> 4;
  const int bh = blockIdx.y, b = bh >> 4, h = bh & 15;
  const int qt = blockIdx.x;
  const int qrow = w * 16 + ql;        // q within block
  const int qg = qt * 64 + qrow;       // q within sequence

  bf16x8 qf0, qf1;
  {
    const unsigned short* qr = Qb + (size_t)(b * T_ + qg) * ldq + h * 64;
    qf0 = *reinterpret_cast<const bf16x8*>(qr + g * 8);
    qf1 = *reinterpret_cast<const bf16x8*>(qr + 32 + g * 8);
  }
  float m_run = -INFINITY, l_run = 0.f;
  f32x4 oacc[4] = {};

  const int nt = CAUSAL ? (qt + 1) : (Tk >> 6);
  const int srow = lane >> 3, skb = lane & 7;

  auto STAGE_KV = [&](int bu, int kt) {
#pragma unroll
    for (int i = 0; i < 2; ++i) {
      const int rloc = i * 32 + w * 8 + srow;
      const int kb = skb ^ (rloc & 7);  // inverse-swizzled source slot
      gload16(Kb + (size_t)(b * Tk + kt * 64 + rloc) * ldk + h * 64 + kb * 8,
              (void*)(Ks[bu] + (i * 32 + w * 8) * 64));
      gload16(Vt + ((size_t)bh * 64 + rloc) * Tk + kt * 64 + kb * 8,
              (void*)(Vs[bu] + (i * 32 + w * 8) * 64));
    }
  };

  STAGE_KV(0, 0);
  __syncthreads();
  int cur = 0;

  for (int kt = 0; kt < nt; ++kt) {
    if (kt + 1 < nt) STAGE_KV(cur ^ 1, kt + 1);  // flies across this whole tile

    // --- S^T = K * Q^T : D[key][q], wave's 16 q columns ---
    f32x4 sacc[4] = {};
#pragma unroll
    for (int kf = 0; kf < 4; ++kf) {
      const int kr = kf * 16 + ql;
      const int sw = ql & 7;
      const bf16x8 k0v = *reinterpret_cast<const bf16x8*>(Ks[cur] + kr * 64 + ((0 + g) ^ sw) * 8);
      const bf16x8 k1v = *reinterpret_cast<const bf16x8*>(Ks[cur] + kr * 64 + ((4 + g) ^ sw) * 8);
      sacc[kf] = __builtin_amdgcn_mfma_f32_16x16x32_bf16(k0v, qf0, sacc[kf], 0, 0, 0);
      sacc[kf] = __builtin_amdgcn_mfma_f32_16x16x32_bf16(k1v, qf1, sacc[kf], 0, 0, 0);
    }

    // --- online softmax: lane's 16 scores all belong to q = qrow ---
    float sc[4][4];
    float tmax = -INFINITY;
#pragma unroll
    for (int kf = 0; kf < 4; ++kf)
#pragma unroll
      for (int r = 0; r < 4; ++r) {
        float v = sacc[kf][r] * 0.125f;  // 1/sqrt(64)
        if (CAUSAL) {
          const int key = kt * 64 + kf * 16 + g * 4 + r;
          if (key > qg) v = -INFINITY;
        }
        sc[kf][r] = v;
        tmax = fmaxf(tmax, v);
      }
    tmax = fmaxf(tmax, __shfl_xor(tmax, 16));
    tmax = fmaxf(tmax, __shfl_xor(tmax, 32));
    const float mnew = fmaxf(m_run, tmax);
    const float scl = __expf(m_run - mnew);  // 0 on first tile (exp(-inf))
    float psum = 0.f;
    unsigned short pb[4][4];
#pragma unroll
    for (int kf = 0; kf < 4; ++kf)
#pragma unroll
      for (int r = 0; r < 4; ++r) {
        const float p = __expf(sc[kf][r] - mnew);  // masked -> exp(-inf) = 0
        psum += p;
        pb[kf][r] = f2bf(p);
      }
    psum += __shfl_xor(psum, 16);
    psum += __shfl_xor(psum, 32);
    l_run = l_run * scl + psum;
    m_run = mnew;
#pragma unroll
    for (int df = 0; df < 4; ++df)
#pragma unroll
      for (int r = 0; r < 4; ++r) oacc[df][r] *= scl;
#pragma unroll
    for (int kf = 0; kf < 4; ++kf) {
      ushort4v p4; p4[0] = pb[kf][0]; p4[1] = pb[kf][1]; p4[2] = pb[kf][2]; p4[3] = pb[kf][3];
      *reinterpret_cast<ushort4v*>(&Pt[qrow][kf * 16 + g * 4]) = p4;
    }
    // Pt visibility only needs LDS ops drained; keep K/V prefetch in flight.
    asm volatile("s_waitcnt lgkmcnt(0)" ::: "memory");
    __builtin_amdgcn_s_barrier();

    // --- O^T += V^T * P^T : D[d][q] ---
    const bf16x8 p0 = *reinterpret_cast<const bf16x8*>(&Pt[qrow][g * 8]);
    const bf16x8 p1 = *reinterpret_cast<const bf16x8*>(&Pt[qrow][32 + g * 8]);
#pragma unroll
    for (int df = 0; df < 4; ++df) {
      const int vr = df * 16 + ql;
      const int sw = ql & 7;
      const bf16x8 v0 = *reinterpret_cast<const bf16x8*>(Vs[cur] + vr * 64 + ((0 + g) ^ sw) * 8);
      const bf16x8 v1 = *reinterpret_cast<const bf16x8*>(Vs[cur] + vr * 64 + ((4 + g) ^ sw) * 8);
      oacc[df] = __builtin_amdgcn_mfma_f32_16x16x32_bf16(v0, p0, oacc[df], 0, 0, 0);
      oacc[df] = __builtin_amdgcn_mfma_f32_16x16x32_bf16(v1, p1, oacc[df], 0, 0, 0);
    }
    __syncthreads();  // Vs/Pt reads done; prefetched K/V resident (vmcnt 0)
    cur ^= 1;
  }

  const float linv = 1.0f / l_run;
  unsigned short* orow = Ob + (size_t)(b * T_ + qg) * C_ + h * 64;
#pragma unroll
  for (int df = 0; df < 4; ++df)
#pragma unroll
    for (int r = 0; r < 4; ++r)
      orow[df * 16 + g * 4 + r] = f2bf(oacc[df][r] * linv);
}

// ---------------------------------------------------------------------------
// Launch. Workspace layout (132 MB total):
//   [0,32M) bf16 transposed weights | [32,36M) ctx bf16
//   [36,52M) lnout | [52,68M) attno | [68,132M) region A (qkv/q+kv/ff1)
// ---------------------------------------------------------------------------
extern "C" void kernel_launch(void* const* d_in, const int* in_sizes, int n_in,
                              void* d_out, int out_size, void* d_ws, size_t ws_size,
                              hipStream_t stream) {
  const float* x    = (const float*)d_in[0];
  const float* ctx  = (const float*)d_in[1];
  const float* ln1g = (const float*)d_in[2];
  const float* ln1b = (const float*)d_in[3];
  const float* ln2g = (const float*)d_in[4];
  const float* ln2b = (const float*)d_in[5];
  const float* ln3g = (const float*)d_in[6];
  const float* ln3b = (const float*)d_in[7];
  const float* Wqkv = (const float*)d_in[8];
  const float* Wsp  = (const float*)d_in[9];
  const float* bsp  = (const float*)d_in[10];
  const float* Wq   = (const float*)d_in[11];
  const float* Wkv  = (const float*)d_in[12];
  const float* Wcp  = (const float*)d_in[13];
  const float* bcp  = (const float*)d_in[14];
  const float* Wf1  = (const float*)d_in[15];
  const float* bf1  = (const float*)d_in[16];
  const float* Wf2  = (const float*)d_in[17];
  const float* bf2  = (const float*)d_in[18];
  float* out = (float*)d_out;

  char* wsb = (char*)d_ws;
  unsigned short* WqkvT = (unsigned short*)(wsb + 0);          // 6 MB
  unsigned short* WspT  = (unsigned short*)(wsb + 6291456);    // 2 MB
  unsigned short* WqT   = (unsigned short*)(wsb + 8388608);    // 2 MB
  unsigned short* WkvT  = (unsigned short*)(wsb + 10485760);   // 4 MB
  unsigned short* WcpT  = (unsigned short*)(wsb + 14680064);   // 2 MB
  unsigned short* Wf1T  = (unsigned short*)(wsb + 16777216);   // 8 MB
  unsigned short* Wf2T  = (unsigned short*)(wsb + 25165824);   // 8 MB
  unsigned short* ctxb  = (unsigned short*)(wsb + 33554432);   // 4 MB
  unsigned short* lnout = (unsigned short*)(wsb + 37748736);   // 16 MB
  unsigned short* attno = (unsigned short*)(wsb + 54525952);   // 16 MB
  char* regA = wsb + 71303168;                                  // 64 MB
  unsigned short* qkvb = (unsigned short*)regA;                // 48 MB
  unsigned short* VtS  = (unsigned short*)(regA + 50331648);   // 16 MB
  unsigned short* qbuf = (unsigned short*)regA;                // 16 MB
  unsigned short* kvb  = (unsigned short*)(regA + 16777216);   // 8 MB
  unsigned short* VtC  = (unsigned short*)(regA + 25165824);   // 4 MB
  unsigned short* ff1o = (unsigned short*)regA;                // 64 MB

  const dim3 blk(256);

  // --- weight/ctx conversion (every call; ws is re-poisoned by harness) ---
  wconvT_kernel<<<dim3(48, 16), blk, 0, stream>>>(Wqkv, WqkvT, 1024, 3072);
  wconvT_kernel<<<dim3(16, 16), blk, 0, stream>>>(Wsp, WspT, 1024, 1024);
  wconvT_kernel<<<dim3(16, 16), blk, 0, stream>>>(Wq, WqT, 1024, 1024);
  wconvT_kernel<<<dim3(32, 16), blk, 0, stream>>>(Wkv, WkvT, 1024, 2048);
  wconvT_kernel<<<dim3(16, 16), blk, 0, stream>>>(Wcp, WcpT, 1024, 1024);
  wconvT_kernel<<<dim3(64, 16), blk, 0, stream>>>(Wf1, Wf1T, 1024, 4096);
  wconvT_kernel<<<dim3(16, 64), blk, 0, stream>>>(Wf2, Wf2T, 4096, 1024);
  f2bf_kernel<<<1024, blk, 0, stream>>>(ctx, ctxb, 262144);

  // --- causal self-attention ---
  ln_kernel<<<8192, blk, 0, stream>>>(x, ln1g, ln1b, lnout);
  gemm_bf16<EPI_NONE><<<dim3(24, 64), blk, 0, stream>>>(
      lnout, WqkvT, nullptr, nullptr, qkvb, 8192, 3072, 1024);
  vtrans_kernel<<<dim3(16, 128), blk, 0, stream>>>(qkvb + 2048, VtS, 3072, 1024);
  attn_mfma<true><<<dim3(16, 128), blk, 0, stream>>>(
      qkvb, qkvb + 1024, VtS, attno, 1024, 3072, 3072);
  gemm_bf16<EPI_BIAS_RESID><<<dim3(8, 64), blk, 0, stream>>>(
      attno, WspT, bsp, x, out, 8192, 1024, 1024);

  // --- cross-attention ---
  ln_kernel<<<8192, blk, 0, stream>>>(out, ln2g, ln2b, lnout);
  gemm_bf16<EPI_NONE><<<dim3(8, 64), blk, 0, stream>>>(
      lnout, WqT, nullptr, nullptr, qbuf, 8192, 1024, 1024);
  gemm_bf16<EPI_NONE><<<dim3(16, 16), blk, 0, stream>>>(
      ctxb, WkvT, nullptr, nullptr, kvb, 2048, 2048, 1024);
  vtrans_kernel<<<dim3(4, 128), blk, 0, stream>>>(kvb + 1024, VtC, 2048, 256);
  attn_mfma<false><<<dim3(16, 128), blk, 0, stream>>>(
      qbuf, kvb, VtC, attno, 256, 1024, 2048);
  gemm_bf16<EPI_BIAS_RESID><<<dim3(8, 64), blk, 0, stream>>>(
      attno, WcpT, bcp, out, out, 8192, 1024, 1024);

  // --- FFN ---
  ln_kernel<<<8192, blk, 0, stream>>>(out, ln3g, ln3b, lnout);
  gemm_bf16<EPI_BIAS_GELU><<<dim3(32, 64), blk, 0, stream>>>(
      lnout, Wf1T, bf1, nullptr, ff1o, 8192, 4096, 1024);
  gemm_bf16<EPI_BIAS_RESID><<<dim3(8, 64), blk, 0, stream>>>(
      ff1o, Wf2T, bf2, out, out, 8192, 1024, 4096);
}

// Round 7
// 659.327 us; speedup vs baseline: 5.5580x; 1.0519x over previous
//
#include <hip/hip_runtime.h>
#include <math.h>

constexpr int B_ = 8, T_ = 1024, S_ = 256, C_ = 1024, H_ = 16, F_ = 4096, D_ = 64;

typedef __attribute__((ext_vector_type(8))) short bf16x8;      // 8 bf16 (4 VGPR) MFMA frag
typedef __attribute__((ext_vector_type(8))) unsigned short ushort8;
typedef __attribute__((ext_vector_type(4))) unsigned short ushort4v;
typedef __attribute__((ext_vector_type(4))) float f32x4;

__device__ __forceinline__ unsigned short f2bf(float f) {  // RN float->bf16
  union { float f; unsigned u; } c; c.f = f;
  unsigned u = c.u;
  u += 0x7FFFu + ((u >> 16) & 1u);
  return (unsigned short)(u >> 16);
}

// async global->LDS, 16B per lane. LDS dest must be wave-uniform base; HW adds lane*16.
__device__ __forceinline__ void gload16(const void* g, void* l) {
  typedef __attribute__((address_space(3))) unsigned int lds_u32;
  typedef __attribute__((address_space(1))) const unsigned int glb_u32;
  __builtin_amdgcn_global_load_lds((glb_u32*)(size_t)g,
                                   (lds_u32*)(unsigned)(size_t)l, 16, 0, 0);
}

// tanh-GELU via one exp (verified absmax-neutral in r6 vs erf at this tolerance)
__device__ __forceinline__ float gelu_fast(float v) {
  return v / (1.0f + __expf(-1.5957691216057308f * v * (1.0f + 0.044715f * v * v)));
}

// ---------------------------------------------------------------------------
// LayerNorm fp32 -> bf16 out. One block/row, 256 threads, float4/thread.
// ---------------------------------------------------------------------------
__global__ __launch_bounds__(256) void ln_kernel(
    const float* __restrict__ x, const float* __restrict__ g,
    const float* __restrict__ b, unsigned short* __restrict__ out) {
  const int row = blockIdx.x;
  const int t = threadIdx.x;
  const float4 v = reinterpret_cast<const float4*>(x + (size_t)row * C_)[t];
  float sum = v.x + v.y + v.z + v.w;
  float ss  = v.x * v.x + v.y * v.y + v.z * v.z + v.w * v.w;
#pragma unroll
  for (int o = 1; o < 64; o <<= 1) {
    sum += __shfl_xor(sum, o);
    ss  += __shfl_xor(ss, o);
  }
  __shared__ float s1[4], s2[4];
  const int wid = t >> 6;
  if ((t & 63) == 0) { s1[wid] = sum; s2[wid] = ss; }
  __syncthreads();
  sum = s1[0] + s1[1] + s1[2] + s1[3];
  ss  = s2[0] + s2[1] + s2[2] + s2[3];
  const float inv = 1.0f / (float)C_;
  const float mu  = sum * inv;
  const float var = ss * inv - mu * mu;
  const float rstd = rsqrtf(var + 1e-5f);
  const float4 gg = reinterpret_cast<const float4*>(g)[t];
  const float4 bb = reinterpret_cast<const float4*>(b)[t];
  ushort4v o4;
  o4[0] = f2bf((v.x - mu) * rstd * gg.x + bb.x);
  o4[1] = f2bf((v.y - mu) * rstd * gg.y + bb.y);
  o4[2] = f2bf((v.z - mu) * rstd * gg.z + bb.z);
  o4[3] = f2bf((v.w - mu) * rstd * gg.w + bb.w);
  *reinterpret_cast<ushort4v*>(out + (size_t)row * C_ + t * 4) = o4;
}

// ---------------------------------------------------------------------------
// Weight convert+transpose: fp32 [K][N] -> bf16 [N][K]. 64x64 tiles.
// ---------------------------------------------------------------------------
__global__ __launch_bounds__(256) void wconvT_kernel(
    const float* __restrict__ W, unsigned short* __restrict__ Wt, int K, int N) {
  __shared__ unsigned short Lt[64][72];  // [n][k]
  const int tid = threadIdx.x;
  const int n0 = blockIdx.x * 64, k0 = blockIdx.y * 64;
#pragma unroll
  for (int j = 0; j < 4; ++j) {
    const int kk = j * 16 + (tid >> 4);
    const float4 v = *reinterpret_cast<const float4*>(W + (size_t)(k0 + kk) * N + n0 + (tid & 15) * 4);
    const int nn = (tid & 15) * 4;
    Lt[nn + 0][kk] = f2bf(v.x);
    Lt[nn + 1][kk] = f2bf(v.y);
    Lt[nn + 2][kk] = f2bf(v.z);
    Lt[nn + 3][kk] = f2bf(v.w);
  }
  __syncthreads();
  const int rr = tid >> 3, ck = tid & 7;
#pragma unroll
  for (int j = 0; j < 2; ++j) {
    const int n = j * 32 + rr;
    *reinterpret_cast<ushort8*>(Wt + (size_t)(n0 + n) * K + k0 + ck * 8) =
        *reinterpret_cast<const ushort8*>(&Lt[n][ck * 8]);
  }
}

// fp32 -> bf16 elementwise (ctx). 8 elems/thread.
__global__ __launch_bounds__(256) void f2bf_kernel(
    const float* __restrict__ in, unsigned short* __restrict__ o, int n8) {
  const int i = blockIdx.x * 256 + threadIdx.x;
  if (i < n8) {
    const float4 a = *reinterpret_cast<const float4*>(in + (size_t)i * 8);
    const float4 b = *reinterpret_cast<const float4*>(in + (size_t)i * 8 + 4);
    ushort8 r;
    r[0] = f2bf(a.x); r[1] = f2bf(a.y); r[2] = f2bf(a.z); r[3] = f2bf(a.w);
    r[4] = f2bf(b.x); r[5] = f2bf(b.y); r[6] = f2bf(b.z); r[7] = f2bf(b.w);
    *reinterpret_cast<ushort8*>(o + (size_t)i * 8) = r;
  }
}

// ---------------------------------------------------------------------------
// V transpose per (b,h): bf16 [Ts][64] (row stride ldsrc) -> bf16 [bh][64][Ts]
// ---------------------------------------------------------------------------
__global__ __launch_bounds__(256) void vtrans_kernel(
    const unsigned short* __restrict__ src, unsigned short* __restrict__ dst,
    int ldsrc, int Ts) {
  __shared__ unsigned short Lt[64][72];  // [d][t]
  const int tid = threadIdx.x;
  const int bh = blockIdx.y, b = bh >> 4, h = bh & 15;
  const int t0 = blockIdx.x * 64;
  const int rr = tid >> 3, ck = tid & 7;
#pragma unroll
  for (int j = 0; j < 2; ++j) {
    const int t = j * 32 + rr;
    const ushort8 v = *reinterpret_cast<const ushort8*>(
        src + (size_t)(b * Ts + t0 + t) * ldsrc + h * 64 + ck * 8);
#pragma unroll
    for (int e = 0; e < 8; ++e) Lt[ck * 8 + e][t] = v[e];
  }
  __syncthreads();
#pragma unroll
  for (int j = 0; j < 2; ++j) {
    const int d = j * 32 + rr;
    *reinterpret_cast<ushort8*>(dst + ((size_t)bh * 64 + d) * Ts + t0 + ck * 8) =
        *reinterpret_cast<const ushort8*>(&Lt[d][ck * 8]);
  }
}

// ---------------------------------------------------------------------------
// 256-class bf16 MFMA GEMM (8-phase-style): C[M,N] = A[M,K] @ Bt[N,K]^T (+epi)
// BM=256, BN_ in {256,128}, BK=64, 512 threads = 8 waves (WMxWN).
// Counted vmcnt: stage tile t+1 (8|6 gloads), wait vmcnt(8|6) == "tile t
// resident, prefetch in flight". Phases: {ds_read frags; barrier; lgkm(0);
// setprio(1); 16 MFMA; setprio(0); barrier}. T2 swizzle byte^=(row&7)<<4 as
// inverse-swizzled global source + swizzled read (gload dest stays linear).
// ---------------------------------------------------------------------------
enum { EPI_NONE = 0, EPI_BIAS_RESID = 1, EPI_BIAS_GELU = 2 };

template <int EPI, int BN_, int WM, int WN>
__global__ __launch_bounds__(512) void gemm256(
    const unsigned short* __restrict__ A, const unsigned short* __restrict__ Bt,
    const float* __restrict__ bias, const float* __restrict__ resid,
    void* __restrict__ Cout, int M, int N, int K) {
  static_assert(WM * WN == 8, "");
  constexpr int MR = 256 / WM;       // per-wave rows
  constexpr int NR = BN_ / WN;       // per-wave cols (= 64)
  constexpr int MFR = MR / 16;       // m-frag repeats (8 or 4)
  static_assert(NR == 64, "");
  constexpr int B_ISS = BN_ / 64;    // gload issues for B tile (4 or 2)
  constexpr int NS = 4 + B_ISS;      // gloads per STAGE (8 or 6)

  __shared__ unsigned short As[2][256 * 64];
  __shared__ unsigned short Bs[2][BN_ * 64];

  const int tid = threadIdx.x;
  const int w = tid >> 6, lane = tid & 63;
  const int ql = lane & 15, g = lane >> 4;
  const int wr = w / WN, wc = w % WN;

  // bijective XCD swizzle on linear block id (all call-site grids %8==0)
  const int nbx = gridDim.x;
  const int nwg = gridDim.x * gridDim.y;
  const int orig = blockIdx.y * nbx + blockIdx.x;
  const int swz = (orig & 7) * (nwg >> 3) + (orig >> 3);
  const int bm = (swz / nbx) * 256;
  const int bn = (swz % nbx) * BN_;

  f32x4 acc[MFR][4] = {};

  auto STAGE = [&](int bu, int k0) {
    char* aDst = (char*)&As[bu][0] + w * 1024;
    char* bDst = (char*)&Bs[bu][0] + w * 1024;
#pragma unroll
    for (int i = 0; i < 4; ++i) {
      const unsigned L = i * 8192u + (unsigned)tid * 16u;
      const int row = (int)(L >> 7);
      const unsigned kb = (L & 127u) ^ ((unsigned)(row & 7) << 4);
      gload16(A + (size_t)(bm + row) * K + k0 + (kb >> 1), aDst + i * 8192);
    }
#pragma unroll
    for (int i = 0; i < B_ISS; ++i) {
      const unsigned L = i * 8192u + (unsigned)tid * 16u;
      const int row = (int)(L >> 7);
      const unsigned kb = (L & 127u) ^ ((unsigned)(row & 7) << 4);
      gload16(Bt + (size_t)(bn + row) * K + k0 + (kb >> 1), bDst + i * 8192);
    }
  };

  STAGE(0, 0);
  int cur = 0;
  const int NT = K >> 6;
  for (int t = 0; t < NT; ++t) {
    if (t + 1 < NT) {
      STAGE(cur ^ 1, (t + 1) * 64);
      if constexpr (NS == 8) asm volatile("s_waitcnt vmcnt(8)" ::: "memory");
      else                   asm volatile("s_waitcnt vmcnt(6)" ::: "memory");
    } else {
      asm volatile("s_waitcnt vmcnt(0)" ::: "memory");
    }
    __builtin_amdgcn_s_barrier();  // tile t fully resident for all waves

    const char* aBase = (const char*)&As[cur][0];
    const char* bBase = (const char*)&Bs[cur][0];
#pragma unroll
    for (int mh = 0; mh < MFR / 4; ++mh) {
      bf16x8 a0[4], a1[4];
#pragma unroll
      for (int m4 = 0; m4 < 4; ++m4) {
        const int row = wr * MR + (mh * 4 + m4) * 16 + ql;
        const unsigned sw = (unsigned)(row & 7) << 4;
        a0[m4] = *(const bf16x8*)(aBase + row * 128 + (unsigned)((g * 16) ^ sw));
        a1[m4] = *(const bf16x8*)(aBase + row * 128 + (unsigned)((64 + g * 16) ^ sw));
      }
#pragma unroll
      for (int nh = 0; nh < 2; ++nh) {
        bf16x8 b0[2], b1[2];
#pragma unroll
        for (int n2 = 0; n2 < 2; ++n2) {
          const int rowb = wc * NR + (nh * 2 + n2) * 16 + ql;
          const unsigned sw = (unsigned)(rowb & 7) << 4;
          b0[n2] = *(const bf16x8*)(bBase + rowb * 128 + (unsigned)((g * 16) ^ sw));
          b1[n2] = *(const bf16x8*)(bBase + rowb * 128 + (unsigned)((64 + g * 16) ^ sw));
        }
        __builtin_amdgcn_s_barrier();
        asm volatile("s_waitcnt lgkmcnt(0)" ::: "memory");
        __builtin_amdgcn_sched_barrier(0);
        __builtin_amdgcn_s_setprio(1);
#pragma unroll
        for (int m4 = 0; m4 < 4; ++m4)
#pragma unroll
          for (int n2 = 0; n2 < 2; ++n2) {
            acc[mh * 4 + m4][nh * 2 + n2] = __builtin_amdgcn_mfma_f32_16x16x32_bf16(
                a0[m4], b0[n2], acc[mh * 4 + m4][nh * 2 + n2], 0, 0, 0);
            acc[mh * 4 + m4][nh * 2 + n2] = __builtin_amdgcn_mfma_f32_16x16x32_bf16(
                a1[m4], b1[n2], acc[mh * 4 + m4][nh * 2 + n2], 0, 0, 0);
          }
        __builtin_amdgcn_s_setprio(0);
        __builtin_amdgcn_s_barrier();
      }
    }
    cur ^= 1;
  }

  // epilogue: C[m = bm+wr*MR+mf*16+g*4+r][n = bn+wc*NR+nf*16+ql]
  float b4[4];
  if (EPI != EPI_NONE) {
#pragma unroll
    for (int nf = 0; nf < 4; ++nf) b4[nf] = bias[bn + wc * NR + nf * 16 + ql];
  }
#pragma unroll
  for (int mf = 0; mf < MFR; ++mf) {
#pragma unroll
    for (int r = 0; r < 4; ++r) {
      const size_t m = (size_t)(bm + wr * MR + mf * 16 + g * 4 + r);
      const int ncol = bn + wc * NR + ql;
      if (EPI == EPI_BIAS_RESID) {
        float* op = (float*)Cout + m * N + ncol;
        const float* rp = resid + m * N + ncol;
#pragma unroll
        for (int nf = 0; nf < 4; ++nf)
          op[nf * 16] = acc[mf][nf][r] + b4[nf] + rp[nf * 16];
      } else {
        unsigned short* op = (unsigned short*)Cout + m * N + ncol;
#pragma unroll
        for (int nf = 0; nf < 4; ++nf) {
          float v = acc[mf][nf][r];
          if (EPI == EPI_BIAS_GELU) v = gelu_fast(v + b4[nf]);
          op[nf * 16] = f2bf(v);
        }
      }
    }
  }
}

// ---------------------------------------------------------------------------
// MFMA flash attention, 2-phase dbuf K/V (unchanged from r6; verified).
// ---------------------------------------------------------------------------
template <bool CAUSAL>
__global__ __launch_bounds__(256) void attn_mfma(
    const unsigned short* __restrict__ Qb, const unsigned short* __restrict__ Kb,
    const unsigned short* __restrict__ Vt, unsigned short* __restrict__ Ob,
    int Tk, int ldq, int ldk) {
  __shared__ unsigned short Ks[2][64 * 64];   // [key][d], swizzled slots
  __shared__ unsigned short Vs[2][64 * 64];   // [d][s],  swizzled slots
  __shared__ unsigned short Pt[64][72];       // [q][s], padded (2-way)
  const int tid = threadIdx.x;
  const int w = tid >> 6, lane = tid & 63;
  const int ql = lane & 15, g = lane >> 4;
  const int bh = blockIdx.y, b = bh >> 4, h = bh & 15;
  const int qt = blockIdx.x;
  const int qrow = w * 16 + ql;        // q within block
  const int qg = qt * 64 + qrow;       // q within sequence

  bf16x8 qf0, qf1;
  {
    const unsigned short* qr = Qb + (size_t)(b * T_ + qg) * ldq + h * 64;
    qf0 = *reinterpret_cast<const bf16x8*>(qr + g * 8);
    qf1 = *reinterpret_cast<const bf16x8*>(qr + 32 + g * 8);
  }
  float m_run = -INFINITY, l_run = 0.f;
  f32x4 oacc[4] = {};

  const int nt = CAUSAL ? (qt + 1) : (Tk >> 6);
  const int srow = lane >> 3, skb = lane & 7;

  auto STAGE_KV = [&](int bu, int kt) {
#pragma unroll
    for (int i = 0; i < 2; ++i) {
      const int rloc = i * 32 + w * 8 + srow;
      const int kb = skb ^ (rloc & 7);  // inverse-swizzled source slot
      gload16(Kb + (size_t)(b * Tk + kt * 64 + rloc) * ldk + h * 64 + kb * 8,
              (void*)(Ks[bu] + (i * 32 + w * 8) * 64));
      gload16(Vt + ((size_t)bh * 64 + rloc) * Tk + kt * 64 + kb * 8,
              (void*)(Vs[bu] + (i * 32 + w * 8) * 64));
    }
  };

  STAGE_KV(0, 0);
  __syncthreads();
  int cur = 0;

  for (int kt = 0; kt < nt; ++kt) {
    if (kt + 1 < nt) STAGE_KV(cur ^ 1, kt + 1);  // flies across this whole tile

    // --- S^T = K * Q^T : D[key][q], wave's 16 q columns ---
    f32x4 sacc[4] = {};
#pragma unroll
    for (int kf = 0; kf < 4; ++kf) {
      const int kr = kf * 16 + ql;
      const int sw = ql & 7;
      const bf16x8 k0v = *reinterpret_cast<const bf16x8*>(Ks[cur] + kr * 64 + ((0 + g) ^ sw) * 8);
      const bf16x8 k1v = *reinterpret_cast<const bf16x8*>(Ks[cur] + kr * 64 + ((4 + g) ^ sw) * 8);
      sacc[kf] = __builtin_amdgcn_mfma_f32_16x16x32_bf16(k0v, qf0, sacc[kf], 0, 0, 0);
      sacc[kf] = __builtin_amdgcn_mfma_f32_16x16x32_bf16(k1v, qf1, sacc[kf], 0, 0, 0);
    }

    // --- online softmax: lane's 16 scores all belong to q = qrow ---
    float sc[4][4];
    float tmax = -INFINITY;
#pragma unroll
    for (int kf = 0; kf < 4; ++kf)
#pragma unroll
      for (int r = 0; r < 4; ++r) {
        float v = sacc[kf][r] * 0.125f;  // 1/sqrt(64)
        if (CAUSAL) {
          const int key = kt * 64 + kf * 16 + g * 4 + r;
          if (key > qg) v = -INFINITY;
        }
        sc[kf][r] = v;
        tmax = fmaxf(tmax, v);
      }
    tmax = fmaxf(tmax, __shfl_xor(tmax, 16));
    tmax = fmaxf(tmax, __shfl_xor(tmax, 32));
    const float mnew = fmaxf(m_run, tmax);
    const float scl = __expf(m_run - mnew);  // 0 on first tile (exp(-inf))
    float psum = 0.f;
    unsigned short pb[4][4];
#pragma unroll
    for (int kf = 0; kf < 4; ++kf)
#pragma unroll
      for (int r = 0; r < 4; ++r) {
        const float p = __expf(sc[kf][r] - mnew);  // masked -> exp(-inf) = 0
        psum += p;
        pb[kf][r] = f2bf(p);
      }
    psum += __shfl_xor(psum, 16);
    psum += __shfl_xor(psum, 32);
    l_run = l_run * scl + psum;
    m_run = mnew;
#pragma unroll
    for (int df = 0; df < 4; ++df)
#pragma unroll
      for (int r = 0; r < 4; ++r) oacc[df][r] *= scl;
#pragma unroll
    for (int kf = 0; kf < 4; ++kf) {
      ushort4v p4; p4[0] = pb[kf][0]; p4[1] = pb[kf][1]; p4[2] = pb[kf][2]; p4[3] = pb[kf][3];
      *reinterpret_cast<ushort4v*>(&Pt[qrow][kf * 16 + g * 4]) = p4;
    }
    // Pt visibility only needs LDS ops drained; keep K/V prefetch in flight.
    asm volatile("s_waitcnt lgkmcnt(0)" ::: "memory");
    __builtin_amdgcn_s_barrier();

    // --- O^T += V^T * P^T : D[d][q] ---
    const bf16x8 p0 = *reinterpret_cast<const bf16x8*>(&Pt[qrow][g * 8]);
    const bf16x8 p1 = *reinterpret_cast<const bf16x8*>(&Pt[qrow][32 + g * 8]);
#pragma unroll
    for (int df = 0; df < 4; ++df) {
      const int vr = df * 16 + ql;
      const int sw = ql & 7;
      const bf16x8 v0 = *reinterpret_cast<const bf16x8*>(Vs[cur] + vr * 64 + ((0 + g) ^ sw) * 8);
      const bf16x8 v1 = *reinterpret_cast<const bf16x8*>(Vs[cur] + vr * 64 + ((4 + g) ^ sw) * 8);
      oacc[df] = __builtin_amdgcn_mfma_f32_16x16x32_bf16(v0, p0, oacc[df], 0, 0, 0);
      oacc[df] = __builtin_amdgcn_mfma_f32_16x16x32_bf16(v1, p1, oacc[df], 0, 0, 0);
    }
    __syncthreads();  // Vs/Pt reads done; prefetched K/V resident (vmcnt 0)
    cur ^= 1;
  }

  const float linv = 1.0f / l_run;
  unsigned short* orow = Ob + (size_t)(b * T_ + qg) * C_ + h * 64;
#pragma unroll
  for (int df = 0; df < 4; ++df)
#pragma unroll
    for (int r = 0; r < 4; ++r)
      orow[df * 16 + g * 4 + r] = f2bf(oacc[df][r] * linv);
}

// ---------------------------------------------------------------------------
// Launch. Workspace layout (132 MB total):
//   [0,32M) bf16 transposed weights | [32,36M) ctx bf16
//   [36,52M) lnout | [52,68M) attno | [68,132M) region A (qkv/q+kv/ff1)
// ---------------------------------------------------------------------------
extern "C" void kernel_launch(void* const* d_in, const int* in_sizes, int n_in,
                              void* d_out, int out_size, void* d_ws, size_t ws_size,
                              hipStream_t stream) {
  const float* x    = (const float*)d_in[0];
  const float* ctx  = (const float*)d_in[1];
  const float* ln1g = (const float*)d_in[2];
  const float* ln1b = (const float*)d_in[3];
  const float* ln2g = (const float*)d_in[4];
  const float* ln2b = (const float*)d_in[5];
  const float* ln3g = (const float*)d_in[6];
  const float* ln3b = (const float*)d_in[7];
  const float* Wqkv = (const float*)d_in[8];
  const float* Wsp  = (const float*)d_in[9];
  const float* bsp  = (const float*)d_in[10];
  const float* Wq   = (const float*)d_in[11];
  const float* Wkv  = (const float*)d_in[12];
  const float* Wcp  = (const float*)d_in[13];
  const float* bcp  = (const float*)d_in[14];
  const float* Wf1  = (const float*)d_in[15];
  const float* bf1  = (const float*)d_in[16];
  const float* Wf2  = (const float*)d_in[17];
  const float* bf2  = (const float*)d_in[18];
  float* out = (float*)d_out;

  char* wsb = (char*)d_ws;
  unsigned short* WqkvT = (unsigned short*)(wsb + 0);          // 6 MB
  unsigned short* WspT  = (unsigned short*)(wsb + 6291456);    // 2 MB
  unsigned short* WqT   = (unsigned short*)(wsb + 8388608);    // 2 MB
  unsigned short* WkvT  = (unsigned short*)(wsb + 10485760);   // 4 MB
  unsigned short* WcpT  = (unsigned short*)(wsb + 14680064);   // 2 MB
  unsigned short* Wf1T  = (unsigned short*)(wsb + 16777216);   // 8 MB
  unsigned short* Wf2T  = (unsigned short*)(wsb + 25165824);   // 8 MB
  unsigned short* ctxb  = (unsigned short*)(wsb + 33554432);   // 4 MB
  unsigned short* lnout = (unsigned short*)(wsb + 37748736);   // 16 MB
  unsigned short* attno = (unsigned short*)(wsb + 54525952);   // 16 MB
  char* regA = wsb + 71303168;                                  // 64 MB
  unsigned short* qkvb = (unsigned short*)regA;                // 48 MB
  unsigned short* VtS  = (unsigned short*)(regA + 50331648);   // 16 MB
  unsigned short* qbuf = (unsigned short*)regA;                // 16 MB
  unsigned short* kvb  = (unsigned short*)(regA + 16777216);   // 8 MB
  unsigned short* VtC  = (unsigned short*)(regA + 25165824);   // 4 MB
  unsigned short* ff1o = (unsigned short*)regA;                // 64 MB

  const dim3 blk(256);
  const dim3 blk512(512);

  // --- weight/ctx conversion (every call; ws is re-poisoned by harness) ---
  wconvT_kernel<<<dim3(48, 16), blk, 0, stream>>>(Wqkv, WqkvT, 1024, 3072);
  wconvT_kernel<<<dim3(16, 16), blk, 0, stream>>>(Wsp, WspT, 1024, 1024);
  wconvT_kernel<<<dim3(16, 16), blk, 0, stream>>>(Wq, WqT, 1024, 1024);
  wconvT_kernel<<<dim3(32, 16), blk, 0, stream>>>(Wkv, WkvT, 1024, 2048);
  wconvT_kernel<<<dim3(16, 16), blk, 0, stream>>>(Wcp, WcpT, 1024, 1024);
  wconvT_kernel<<<dim3(64, 16), blk, 0, stream>>>(Wf1, Wf1T, 1024, 4096);
  wconvT_kernel<<<dim3(16, 64), blk, 0, stream>>>(Wf2, Wf2T, 4096, 1024);
  f2bf_kernel<<<1024, blk, 0, stream>>>(ctx, ctxb, 262144);

  // --- causal self-attention ---
  ln_kernel<<<8192, blk, 0, stream>>>(x, ln1g, ln1b, lnout);
  gemm256<EPI_NONE, 256, 2, 4><<<dim3(12, 32), blk512, 0, stream>>>(
      lnout, WqkvT, nullptr, nullptr, qkvb, 8192, 3072, 1024);
  vtrans_kernel<<<dim3(16, 128), blk, 0, stream>>>(qkvb + 2048, VtS, 3072, 1024);
  attn_mfma<true><<<dim3(16, 128), blk, 0, stream>>>(
      qkvb, qkvb + 1024, VtS, attno, 1024, 3072, 3072);
  gemm256<EPI_BIAS_RESID, 128, 4, 2><<<dim3(8, 32), blk512, 0, stream>>>(
      attno, WspT, bsp, x, out, 8192, 1024, 1024);

  // --- cross-attention ---
  ln_kernel<<<8192, blk, 0, stream>>>(out, ln2g, ln2b, lnout);
  gemm256<EPI_NONE, 128, 4, 2><<<dim3(8, 32), blk512, 0, stream>>>(
      lnout, WqT, nullptr, nullptr, qbuf, 8192, 1024, 1024);
  gemm256<EPI_NONE, 128, 4, 2><<<dim3(16, 8), blk512, 0, stream>>>(
      ctxb, WkvT, nullptr, nullptr, kvb, 2048, 2048, 1024);
  vtrans_kernel<<<dim3(4, 128), blk, 0, stream>>>(kvb + 1024, VtC, 2048, 256);
  attn_mfma<false><<<dim3(16, 128), blk, 0, stream>>>(
      qbuf, kvb, VtC, attno, 256, 1024, 2048);
  gemm256<EPI_BIAS_RESID, 128, 4, 2><<<dim3(8, 32), blk512, 0, stream>>>(
      attno, WcpT, bcp, out, out, 8192, 1024, 1024);

  // --- FFN ---
  ln_kernel<<<8192, blk, 0, stream>>>(out, ln3g, ln3b, lnout);
  gemm256<EPI_BIAS_GELU, 256, 2, 4><<<dim3(16, 32), blk512, 0, stream>>>(
      lnout, Wf1T, bf1, nullptr, ff1o, 8192, 4096, 1024);
  gemm256<EPI_BIAS_RESID, 128, 4, 2><<<dim3(8, 32), blk512, 0, stream>>>(
      ff1o, Wf2T, bf2, out, out, 8192, 1024, 4096);
}